// Round 1
// baseline (506.181 us; speedup 1.0000x reference)
//
#include <hip/hip_runtime.h>

// Problem constants (match reference)
#define BB 2
#define HH 32
#define LL 4096
#define DD 128
#define TT 2048
#define GG 4

// Main cache fill: one float4 per thread-iteration, per (b,h,l,d4).
// Priority: l==fill_indices[h] -> step ; l<T -> val ; else -> input cache.
__global__ __launch_bounds__(256) void kv_fill(
    const float4* __restrict__ k_cache, const float4* __restrict__ v_cache,
    const float4* __restrict__ k_val,   const float4* __restrict__ v_val,
    const int*    __restrict__ fill_indices,
    const float4* __restrict__ k_step,  const float4* __restrict__ v_step,
    float4* __restrict__ outK, float4* __restrict__ outV)
{
    const long total = (long)BB * HH * LL * (DD / 4);   // 8,388,608 float4
    const long stride = (long)gridDim.x * blockDim.x;
    for (long i = (long)blockIdx.x * blockDim.x + threadIdx.x; i < total; i += stride) {
        const int d4 = (int)(i & 31);            // D/4 = 32
        const int l  = (int)((i >> 5) & (LL - 1));
        const int bh = (int)(i >> 17);           // b*H + h
        const int h  = bh & (HH - 1);
        const int fi = fill_indices[h];
        float4 kv, vv;
        if (l == fi) {
            const int s = bh * (DD / 4) + d4;    // k_step[b,h,0,d]
            kv = k_step[s];
            vv = v_step[s];
        } else if (l < TT) {
            const long s = ((long)bh * TT + l) * (DD / 4) + d4;
            kv = k_val[s];
            vv = v_val[s];
        } else {
            kv = k_cache[i];
            vv = v_cache[i];
        }
        outK[i] = kv;
        outV[i] = vv;
    }
}

// pos fill: priority step > global-mark(L) > input_pos[l] > original pos.
// Output buffer is read back as float32, so write float-encoded values.
__global__ __launch_bounds__(256) void pos_fill(
    const int* __restrict__ pos_in,
    const int* __restrict__ input_pos,
    const int* __restrict__ fill_indices,
    const int* __restrict__ input_pos_step,
    float* __restrict__ outPos)
{
    const int i = blockIdx.x * blockDim.x + threadIdx.x;  // B*H*L = 262,144
    if (i >= BB * HH * LL) return;
    const int l = i & (LL - 1);
    const int h = (i >> 12) & (HH - 1);
    const int fi = fill_indices[h];
    int p;
    if (l == fi)      p = input_pos_step[0];
    else if (l < GG)  p = LL;
    else if (l < TT)  p = input_pos[l];
    else              p = pos_in[i];
    outPos[i] = (float)p;
}

extern "C" void kernel_launch(void* const* d_in, const int* in_sizes, int n_in,
                              void* d_out, int out_size, void* d_ws, size_t ws_size,
                              hipStream_t stream) {
    const float* k_cache = (const float*)d_in[0];
    const float* v_cache = (const float*)d_in[1];
    const int*   pos_in  = (const int*)d_in[2];
    const int*   input_pos = (const int*)d_in[3];
    const float* k_val   = (const float*)d_in[4];
    const float* v_val   = (const float*)d_in[5];
    const int*   fill_indices = (const int*)d_in[6];
    const float* k_step  = (const float*)d_in[7];
    const float* v_step  = (const float*)d_in[8];
    const int*   input_pos_step = (const int*)d_in[9];

    const long KC = (long)BB * HH * LL * DD;   // 33,554,432 floats per cache
    float* outK = (float*)d_out;
    float* outV = outK + KC;
    float* outPos = outV + KC;                 // pos written as float values

    // Memory-bound: cap grid, grid-stride (G11).
    kv_fill<<<2048, 256, 0, stream>>>(
        (const float4*)k_cache, (const float4*)v_cache,
        (const float4*)k_val,   (const float4*)v_val,
        fill_indices,
        (const float4*)k_step,  (const float4*)v_step,
        (float4*)outK, (float4*)outV);

    pos_fill<<<(BB * HH * LL) / 256, 256, 0, stream>>>(
        pos_in, input_pos, fill_indices, input_pos_step, outPos);
}